// Round 12
// baseline (271.899 us; speedup 1.0000x reference)
//
#include <hip/hip_runtime.h>
#include <stdint.h>
#include <math.h>

#define HW   4096
#define NB   8
#define NC   512
#define C2   256
#define PT   32     // p-tile per block in argmax kernel
#define QC   256    // q-chunk (4 k per lane via one float4)
#define NPAIR 8     // pairs of q-chunks per dispatch; dead pairs exit

// ---------- ws layout (bytes) ----------
#define WS_PACKED 0         // u64 packed[8*4096]            = 262144
#define WS_Q0     393216    // i32 q0list[4096]              = 16384
#define WS_P1     409600    // i32 p1list[4096]              = 16384
#define WS_CNT    425984    // i32 cnt[2]
#define WS_INVC   558080    // f32 invc[8*4096]              = 131072

__device__ __forceinline__ unsigned long long mkkey(float v, unsigned q) {
    unsigned u = __float_as_uint(v);
    u = (u & 0x80000000u) ? ~u : (u | 0x80000000u);   // monotone float -> u32
    return ((unsigned long long)u << 32) | (unsigned long long)(0xFFFFFFFFu - q);
}

// Packed scratch lives in d_out's shift region (channels [512,768) of batch b)
// = 1M floats per batch: lfc (C2 x ns) then ffc (C2 x ms). Written by
// pack_kernel, read by invc/argmax, then fully overwritten by shift_kernel.
__device__ __forceinline__ float* lfc_region(float* out, int b) {
    return out + ((size_t)b * 768 + 512) * HW;
}

// --- 1. deterministic sorted compaction of flag into p1 (flag==1) / q0 (flag==0)
__global__ void compact_kernel(const int* __restrict__ flag, int* __restrict__ q0,
                               int* __restrict__ p1, int* __restrict__ cnt) {
    __shared__ int c1s[256];
    int t = threadIdx.x;
    int f[16]; int n1 = 0;
    #pragma unroll
    for (int j = 0; j < 16; ++j) { f[j] = flag[t*16 + j]; n1 += (f[j] == 1); }
    c1s[t] = n1;
    __syncthreads();
    if (t == 0) {
        int run = 0;
        for (int i = 0; i < 256; ++i) { int v = c1s[i]; c1s[i] = run; run += v; }
        cnt[0] = run;          // n1
        cnt[1] = HW - run;     // n0
    }
    __syncthreads();
    int b1 = c1s[t];
    int b0 = t*16 - c1s[t];
    for (int j = 0; j < 16; ++j) {
        int i = t*16 + j;
        if (f[j] == 1) p1[b1++] = i; else q0[b0++] = i;
    }
}

// --- 2. fused copy + pack. Block (b, cy) reads row x[b][cy] once:
//     - coalesced copy: out[b][cy][i] = x[b][cy][i]
//     - cy <  256 (former): ffc[cy][m] = xrow[p1[m]]
//     - cy >= 256 (latter): lfc[cy-256][k] = xrow[q0[k]]
__global__ void pack_kernel(const float* __restrict__ x,
                            const int* __restrict__ q0, const int* __restrict__ p1,
                            const int* __restrict__ cnt, float* __restrict__ out) {
    int b = blockIdx.z, cy = blockIdx.y;
    int i = blockIdx.x * 256 + threadIdx.x;
    int n1 = cnt[0], n0 = cnt[1];
    int ns = (n0 + 3) & ~3, ms = (n1 + 3) & ~3;
    const float* xrow = x + ((size_t)b * NC + cy) * HW;
    out[((size_t)b * 768 + cy) * HW + i] = xrow[i];      // fused copy
    if (cy < C2) {
        if (i < n1) {
            float* ffc = lfc_region(out, b) + (size_t)C2 * ns;
            ffc[(size_t)cy * ms + i] = xrow[p1[i]];
        }
    } else {
        int c = cy - C2;
        if (i < n0) {
            float* lfc = lfc_region(out, b);
            lfc[(size_t)c * ns + i] = xrow[q0[i]];
        }
    }
}

// --- 2b. invc from packed lfc (coalesced; same c-ascending fp32 sum order
//     as the original norm kernel -> bit-identical values at q0 columns)
__global__ void invc_kernel(const float* __restrict__ out, const int* __restrict__ cnt,
                            float* __restrict__ invc) {
    int b = blockIdx.y;
    int n0 = cnt[1];
    int ns = (n0 + 3) & ~3;
    int k = blockIdx.x * 256 + threadIdx.x;
    if (k >= n0) return;
    const float* lfc = lfc_region((float*)out, b) + k;
    float s = 0.f;
    #pragma unroll 8
    for (int c = 0; c < C2; ++c) {
        float v = lfc[(size_t)c * ns];
        s = fmaf(v, v, s);
    }
    invc[b * HW + k] = 1.0f / fmaxf(sqrtf(s), 1e-8f);
}

// one c-row of FMAs: 8 p (from LDS b128 x2) x 4 k (register float4 F)
#define ROWFMA(CC, F) {                                                   \
    const float4* arow = (const float4*)&sff[CC][tp * 8];                 \
    float4 a0 = arow[0], a1 = arow[1];                                    \
    float av[8] = {a0.x, a0.y, a0.z, a0.w, a1.x, a1.y, a1.z, a1.w};       \
    _Pragma("unroll")                                                     \
    for (int pi = 0; pi < 8; ++pi) {                                      \
        acc[pi][0] = fmaf(av[pi], F.x, acc[pi][0]);                       \
        acc[pi][1] = fmaf(av[pi], F.y, acc[pi][1]);                       \
        acc[pi][2] = fmaf(av[pi], F.z, acc[pi][2]);                       \
        acc[pi][3] = fmaf(av[pi], F.w, acc[pi][3]);                       \
    } }

// --- 3. cos + argmax over unmasked q, merged via packed atomicMax
//     1D grid XCD-swizzled (bid&7 = batch -> XCD; 4MB lfc+ffc per batch
//     pinned to one XCD L2; R9: FETCH 148->16.6 MB).
//     TWO q-chunks per block, sequential: live blocks = 32 tiles x 6 pairs
//     x 8 b = 1536 = 6/CU < 8-residency -> one balanced round (R11's
//     12-live/8-resident ran rounds of 8+4 = 48% occupancy).
//     Depth-4 rotation-free prefetch: f0..f3 reloaded in place (no movs);
//     prefetch survives the h-barrier in registers; chunk-end overrun
//     lands in ffc scratch (valid, unused). VGPR ~58 < 64 cliff.
//     NOTE: no min-waves clamp in launch_bounds — (256,4) forced VGPR=64
//     and spilled acc to scratch (13 GB HBM, 7x regression in R3).
__global__ void __launch_bounds__(256) argmax_kernel(
        float* __restrict__ out, const float* __restrict__ invc,
        const int* __restrict__ q0, const int* __restrict__ p1,
        const int* __restrict__ cnt, unsigned long long* __restrict__ packed) {
    int bid   = blockIdx.x;
    int b     = bid & 7;
    int s     = bid >> 3;
    int pair  = s >> 5;
    int tile  = s & 31;
    int n1 = cnt[0], n0 = cnt[1];
    if (tile * PT >= n1) return;
    if (pair * 2 * QC >= n0) return;
    int ns = (n0 + 3) & ~3, ms = (n1 + 3) & ~3;

    __shared__ float sff[128][PT];   // ff half-tile: [c][p] 16 KB

    int t = threadIdx.x;
    int tp = t >> 6;   // wave id -> 8-p sub-tile
    int tq = t & 63;   // lane    -> k group of 4

    const float* lfc = lfc_region(out, b);
    const float* ffc = lfc + (size_t)C2 * ns;
    bool fulltile = (tile * PT + PT <= n1);

    float best[8];
    int   bq[8];
    #pragma unroll
    for (int pi = 0; pi < 8; ++pi) { best[pi] = -INFINITY; bq[pi] = 0x7FFFFFFF; }

    for (int chunk = pair * 2; chunk < pair * 2 + 2 && chunk * QC < n0; ++chunk) {
        int kbase = chunk * QC + tq * 4;   // 16B aligned
        const float* r = lfc + kbase;      // row 0 of this chunk's k-slice
        float4 f0 = *(const float4*)(r);
        float4 f1 = *(const float4*)(r + (size_t)ns);
        float4 f2 = *(const float4*)(r + 2 * (size_t)ns);
        float4 f3 = *(const float4*)(r + 3 * (size_t)ns);

        float acc[8][4];
        #pragma unroll
        for (int pi = 0; pi < 8; ++pi)
            #pragma unroll
            for (int j = 0; j < 4; ++j) acc[pi][j] = 0.f;

        for (int h = 0; h < 2; ++h) {
            __syncthreads();   // all waves done with previous sff contents
            if (fulltile) {
                #pragma unroll
                for (int k = 0; k < 4; ++k) {       // 1024 float4 / 256 threads
                    int i4 = t + (k << 8);
                    int c = i4 >> 3, jg = i4 & 7;
                    ((float4*)sff)[i4] =
                        *(const float4*)&ffc[(size_t)(h * 128 + c) * ms + tile * PT + jg * 4];
                }
            } else {
                #pragma unroll
                for (int k = 0; k < 4; ++k) {
                    int i4 = t + (k << 8);
                    int c = i4 >> 3, jg = i4 & 7;
                    const float* src = &ffc[(size_t)(h * 128 + c) * ms];
                    int m0 = tile * PT + jg * 4;
                    float4 v;
                    v.x = (m0 + 0 < n1) ? src[m0 + 0] : 0.f;
                    v.y = (m0 + 1 < n1) ? src[m0 + 1] : 0.f;
                    v.z = (m0 + 2 < n1) ? src[m0 + 2] : 0.f;
                    v.w = (m0 + 3 < n1) ? src[m0 + 3] : 0.f;
                    ((float4*)sff)[i4] = v;
                }
            }
            __syncthreads();

            for (int cc = 0; cc < 128; cc += 4) {
                // depth-4, rotation-free: consume f_i, reload f_i from row+4
                ROWFMA(cc,     f0); f0 = *(const float4*)(r + 4 * (size_t)ns);
                ROWFMA(cc + 1, f1); f1 = *(const float4*)(r + 5 * (size_t)ns);
                ROWFMA(cc + 2, f2); f2 = *(const float4*)(r + 6 * (size_t)ns);
                ROWFMA(cc + 3, f3); f3 = *(const float4*)(r + 7 * (size_t)ns);
                r += 4 * (size_t)ns;
            }
        }

        // merge this chunk into best/bq (ties resolve to smallest q; chunks
        // ascend in q, and strict > keeps the earlier chunk on equal value)
        #pragma unroll
        for (int j = 0; j < 4; ++j) {
            int k = kbase + j;
            if (k >= n0) continue;
            float sc = invc[b * HW + k];
            int   q  = q0[k];
            #pragma unroll
            for (int pi = 0; pi < 8; ++pi) {
                float cv = acc[pi][j] * sc;
                if (cv > best[pi] || (cv == best[pi] && q < bq[pi])) {
                    best[pi] = cv; bq[pi] = q;
                }
            }
        }
    }

    // wave reduce (all 64 lanes share the same 8 p's)
    #pragma unroll
    for (int m = 1; m < 64; m <<= 1) {
        #pragma unroll
        for (int pi = 0; pi < 8; ++pi) {
            float ov = __shfl_xor(best[pi], m);
            int   oq = __shfl_xor(bq[pi], m);
            if (ov > best[pi] || (ov == best[pi] && oq < bq[pi])) {
                best[pi] = ov; bq[pi] = oq;
            }
        }
    }
    if (tq == 0) {
        #pragma unroll
        for (int pi = 0; pi < 8; ++pi) {
            int pidx = tile * PT + tp * 8 + pi;
            int p = (pidx < n1) ? p1[pidx] : -1;
            if (p >= 0)
                atomicMax(&packed[(size_t)b * HW + p], mkkey(best[pi], (unsigned)bq[pi]));
        }
    }
}

// --- 4. shift writeback with inline decode:
//     out[b, 512+c, p] = flag[p] ? lf[b, c, argmax_q(packed)] : 0
//     (fully overwrites the lfc/ffc scratch region — must run after argmax)
__global__ void shift_kernel(const float* __restrict__ x, const int* __restrict__ flag,
                             const unsigned long long* __restrict__ packed,
                             float* __restrict__ out) {
    int cc = blockIdx.x, b = blockIdx.y;
    const float* lfrow = x + ((size_t)b * NC + C2 + cc) * HW;
    float*       orow  = out + ((size_t)b * 768 + 512 + cc) * HW;
    const unsigned long long* pk = packed + (size_t)b * HW;
    for (int p = threadIdx.x; p < HW; p += 256) {
        float v = 0.f;
        if (flag[p] == 1) {
            unsigned low = (unsigned)(pk[p] & 0xFFFFFFFFull);
            int q = (int)((0xFFFFFFFFu - low) & (HW - 1));
            v = lfrow[q];
        }
        orow[p] = v;
    }
}

extern "C" void kernel_launch(void* const* d_in, const int* in_sizes, int n_in,
                              void* d_out, int out_size, void* d_ws, size_t ws_size,
                              hipStream_t stream) {
    const float* x    = (const float*)d_in[0];
    const int*   flag = (const int*)d_in[1];
    float*       out  = (float*)d_out;
    char*        ws   = (char*)d_ws;

    unsigned long long* packed = (unsigned long long*)(ws + WS_PACKED);
    int*   q0   = (int*)(ws + WS_Q0);
    int*   p1   = (int*)(ws + WS_P1);
    int*   cnt  = (int*)(ws + WS_CNT);
    float* invc = (float*)(ws + WS_INVC);

    hipMemsetAsync(packed, 0, (size_t)NB * HW * sizeof(unsigned long long), stream);

    compact_kernel<<<1, 256, 0, stream>>>(flag, q0, p1, cnt);
    pack_kernel<<<dim3(HW / 256, NC, NB), 256, 0, stream>>>(x, q0, p1, cnt, out);
    invc_kernel<<<dim3(HW / 256, NB), 256, 0, stream>>>(out, cnt, invc);
    argmax_kernel<<<dim3(NB * NPAIR * 32), 256, 0, stream>>>(out, invc, q0, p1, cnt, packed);
    shift_kernel<<<dim3(C2, NB), 256, 0, stream>>>(x, flag, packed, out);
}

// Round 13
// 257.241 us; speedup vs baseline: 1.0570x; 1.0570x over previous
//
#include <hip/hip_runtime.h>
#include <stdint.h>
#include <math.h>

#define HW   4096
#define NB   8
#define NC   512
#define C2   256
#define QC   256    // q-chunk per block (4 k per lane via one float4)
#define NT1  128    // p-tiles of 8 (n1 = 1024 for this fixed flag)
#define NCH  12     // q-chunks (n0 = 3072 for this fixed flag)

// ---------- ws layout (bytes) ----------
#define WS_PACKED 0         // u64 packed[8*4096]            = 262144
#define WS_Q0     393216    // i32 q0list[4096]              = 16384
#define WS_P1     409600    // i32 p1list[4096]              = 16384
#define WS_CNT    425984    // i32 cnt[2]
#define WS_INVC   558080    // f32 invc[8*4096]              = 131072

__device__ __forceinline__ unsigned long long mkkey(float v, unsigned q) {
    unsigned u = __float_as_uint(v);
    u = (u & 0x80000000u) ? ~u : (u | 0x80000000u);   // monotone float -> u32
    return ((unsigned long long)u << 32) | (unsigned long long)(0xFFFFFFFFu - q);
}

// Packed scratch lives in d_out's shift region (channels [512,768) of batch b)
// = 1M floats per batch: lfc (C2 x ns) then ffc (C2 x ms). Written by
// pack_kernel, read by invc/argmax, then fully overwritten by shift_kernel.
__device__ __forceinline__ float* lfc_region(float* out, int b) {
    return out + ((size_t)b * 768 + 512) * HW;
}

// --- 1. deterministic sorted compaction of flag into p1 (flag==1) / q0 (flag==0)
__global__ void compact_kernel(const int* __restrict__ flag, int* __restrict__ q0,
                               int* __restrict__ p1, int* __restrict__ cnt) {
    __shared__ int c1s[256];
    int t = threadIdx.x;
    int f[16]; int n1 = 0;
    #pragma unroll
    for (int j = 0; j < 16; ++j) { f[j] = flag[t*16 + j]; n1 += (f[j] == 1); }
    c1s[t] = n1;
    __syncthreads();
    if (t == 0) {
        int run = 0;
        for (int i = 0; i < 256; ++i) { int v = c1s[i]; c1s[i] = run; run += v; }
        cnt[0] = run;          // n1
        cnt[1] = HW - run;     // n0
    }
    __syncthreads();
    int b1 = c1s[t];
    int b0 = t*16 - c1s[t];
    for (int j = 0; j < 16; ++j) {
        int i = t*16 + j;
        if (f[j] == 1) p1[b1++] = i; else q0[b0++] = i;
    }
}

// --- 2. fused copy + pack. Block (b, cy) reads row x[b][cy] once:
//     - coalesced copy: out[b][cy][i] = x[b][cy][i]
//     - cy <  256 (former): ffc[cy][m] = xrow[p1[m]]
//     - cy >= 256 (latter): lfc[cy-256][k] = xrow[q0[k]]
__global__ void pack_kernel(const float* __restrict__ x,
                            const int* __restrict__ q0, const int* __restrict__ p1,
                            const int* __restrict__ cnt, float* __restrict__ out) {
    int b = blockIdx.z, cy = blockIdx.y;
    int i = blockIdx.x * 256 + threadIdx.x;
    int n1 = cnt[0], n0 = cnt[1];
    int ns = (n0 + 3) & ~3, ms = (n1 + 3) & ~3;
    const float* xrow = x + ((size_t)b * NC + cy) * HW;
    out[((size_t)b * 768 + cy) * HW + i] = xrow[i];      // fused copy
    if (cy < C2) {
        if (i < n1) {
            float* ffc = lfc_region(out, b) + (size_t)C2 * ns;
            ffc[(size_t)cy * ms + i] = xrow[p1[i]];
        }
    } else {
        int c = cy - C2;
        if (i < n0) {
            float* lfc = lfc_region(out, b);
            lfc[(size_t)c * ns + i] = xrow[q0[i]];
        }
    }
}

// --- 2b. invc from packed lfc (coalesced; same c-ascending fp32 sum order
//     as the original norm kernel -> bit-identical values at q0 columns)
__global__ void invc_kernel(const float* __restrict__ out, const int* __restrict__ cnt,
                            float* __restrict__ invc) {
    int b = blockIdx.y;
    int n0 = cnt[1];
    int ns = (n0 + 3) & ~3;
    int k = blockIdx.x * 256 + threadIdx.x;
    if (k >= n0) return;
    const float* lfc = lfc_region((float*)out, b) + k;
    float s = 0.f;
    #pragma unroll 8
    for (int c = 0; c < C2; ++c) {
        float v = lfc[(size_t)c * ns];
        s = fmaf(v, v, s);
    }
    invc[b * HW + k] = 1.0f / fmaxf(sqrtf(s), 1e-8f);
}

// one c-row of FMAs: 8 p (wave-uniform, from A0/A1) x 4 k (per-lane float4 F)
#define ROWF(A0, A1, F) {                                                 \
    float av[8] = {A0.x, A0.y, A0.z, A0.w, A1.x, A1.y, A1.z, A1.w};       \
    float bv[4] = {F.x, F.y, F.z, F.w};                                   \
    _Pragma("unroll")                                                     \
    for (int pi = 0; pi < 8; ++pi) {                                      \
        _Pragma("unroll")                                                 \
        for (int j = 0; j < 4; ++j)                                       \
            acc[pi][j] = fmaf(av[pi], bv[j], acc[pi][j]);                 \
    } }

#define LDA(A0, A1, C) { const float* fa_ = fb + (size_t)(C) * ms;        \
    A0 = *(const float4*)fa_; A1 = *(const float4*)(fa_ + 4); }
#define LDF(F, C) F = *(const float4*)(rb + (size_t)(C) * ns);

// --- 3. cos + argmax, LDS-FREE single-wave blocks.
//     Block = 1 wave = 64 threads. p-tile (8 p's) comes from blockIdx ->
//     the ff row address is PROVABLY wave-uniform -> scalar loads (s_load,
//     scalar pipe, zero VALU cost), no LDS, no barriers, no staging loop.
//     (R11/R12 post-mortem: VALU-busy time pinned at ~137us vs 82us FMA
//     floor -> ~40% of issue was LDS-staging/mov/addr overhead.)
//     Per row: 32 FMA + 1 global float4 (lf) + 1 uniform 32B read (ff).
//     Rotation-free depth-4 prefetch on both streams (~256cy cover >= L2).
//     Grid = 8 b x 128 tiles x 12 chunks (exact for the fixed flag;
//     runtime guards keep correctness if counts shrink). bid&7 = batch ->
//     XCD pin: 4MB lfc+ffc per batch in one XCD L2 (R9: FETCH 148->16.6MB).
__global__ void __launch_bounds__(64) argmax_kernel(
        float* __restrict__ out, const float* __restrict__ invc,
        const int* __restrict__ q0, const int* __restrict__ p1,
        const int* __restrict__ cnt, unsigned long long* __restrict__ packed) {
    int bid   = blockIdx.x;
    int b     = bid & 7;
    int s     = bid >> 3;
    int tile  = s & (NT1 - 1);
    int chunk = s >> 7;
    int n1 = cnt[0], n0 = cnt[1];
    if (tile * 8 >= n1) return;
    if (chunk * QC >= n0) return;
    int ns = (n0 + 3) & ~3, ms = (n1 + 3) & ~3;

    int lane = threadIdx.x;                 // 0..63
    const float* lfc = lfc_region(out, b);
    const float* ffc = lfc + (size_t)C2 * ns;
    int kbase = chunk * QC + lane * 4;      // 16B aligned

    const float* fb = ffc + tile * 8;       // wave-uniform base
    const float* rb = lfc + kbase;          // per-lane base

    float4 aA0, aA1, aB0, aB1, aC0, aC1, aD0, aD1;
    float4 f0, f1, f2, f3;
    LDA(aA0, aA1, 0) LDA(aB0, aB1, 1) LDA(aC0, aC1, 2) LDA(aD0, aD1, 3)
    LDF(f0, 0) LDF(f1, 1) LDF(f2, 2) LDF(f3, 3)

    float acc[8][4];
    #pragma unroll
    for (int pi = 0; pi < 8; ++pi)
        #pragma unroll
        for (int j = 0; j < 4; ++j) acc[pi][j] = 0.f;

    int cc = 0;
    for (; cc < C2 - 4; cc += 4) {
        ROWF(aA0, aA1, f0); LDA(aA0, aA1, cc + 4); LDF(f0, cc + 4);
        ROWF(aB0, aB1, f1); LDA(aB0, aB1, cc + 5); LDF(f1, cc + 5);
        ROWF(aC0, aC1, f2); LDA(aC0, aC1, cc + 6); LDF(f2, cc + 6);
        ROWF(aD0, aD1, f3); LDA(aD0, aD1, cc + 7); LDF(f3, cc + 7);
    }
    ROWF(aA0, aA1, f0); ROWF(aB0, aB1, f1);
    ROWF(aC0, aC1, f2); ROWF(aD0, aD1, f3);

    float best[8];
    int   bq[8];
    #pragma unroll
    for (int pi = 0; pi < 8; ++pi) { best[pi] = -INFINITY; bq[pi] = 0x7FFFFFFF; }

    #pragma unroll
    for (int j = 0; j < 4; ++j) {
        int k = kbase + j;
        if (k >= n0) continue;
        float sc = invc[b * HW + k];
        int   q  = q0[k];
        #pragma unroll
        for (int pi = 0; pi < 8; ++pi) {
            float cv = acc[pi][j] * sc;
            if (cv > best[pi] || (cv == best[pi] && q < bq[pi])) {
                best[pi] = cv; bq[pi] = q;
            }
        }
    }

    // wave reduce (all 64 lanes share the same 8 p's)
    #pragma unroll
    for (int m = 1; m < 64; m <<= 1) {
        #pragma unroll
        for (int pi = 0; pi < 8; ++pi) {
            float ov = __shfl_xor(best[pi], m);
            int   oq = __shfl_xor(bq[pi], m);
            if (ov > best[pi] || (ov == best[pi] && oq < bq[pi])) {
                best[pi] = ov; bq[pi] = oq;
            }
        }
    }
    if (lane == 0) {
        #pragma unroll
        for (int pi = 0; pi < 8; ++pi) {
            int pidx = tile * 8 + pi;
            int p = (pidx < n1) ? p1[pidx] : -1;
            if (p >= 0)
                atomicMax(&packed[(size_t)b * HW + p], mkkey(best[pi], (unsigned)bq[pi]));
        }
    }
}

// --- 4. shift writeback with inline decode:
//     out[b, 512+c, p] = flag[p] ? lf[b, c, argmax_q(packed)] : 0
//     (fully overwrites the lfc/ffc scratch region — must run after argmax)
__global__ void shift_kernel(const float* __restrict__ x, const int* __restrict__ flag,
                             const unsigned long long* __restrict__ packed,
                             float* __restrict__ out) {
    int cc = blockIdx.x, b = blockIdx.y;
    const float* lfrow = x + ((size_t)b * NC + C2 + cc) * HW;
    float*       orow  = out + ((size_t)b * 768 + 512 + cc) * HW;
    const unsigned long long* pk = packed + (size_t)b * HW;
    for (int p = threadIdx.x; p < HW; p += 256) {
        float v = 0.f;
        if (flag[p] == 1) {
            unsigned low = (unsigned)(pk[p] & 0xFFFFFFFFull);
            int q = (int)((0xFFFFFFFFu - low) & (HW - 1));
            v = lfrow[q];
        }
        orow[p] = v;
    }
}

extern "C" void kernel_launch(void* const* d_in, const int* in_sizes, int n_in,
                              void* d_out, int out_size, void* d_ws, size_t ws_size,
                              hipStream_t stream) {
    const float* x    = (const float*)d_in[0];
    const int*   flag = (const int*)d_in[1];
    float*       out  = (float*)d_out;
    char*        ws   = (char*)d_ws;

    unsigned long long* packed = (unsigned long long*)(ws + WS_PACKED);
    int*   q0   = (int*)(ws + WS_Q0);
    int*   p1   = (int*)(ws + WS_P1);
    int*   cnt  = (int*)(ws + WS_CNT);
    float* invc = (float*)(ws + WS_INVC);

    hipMemsetAsync(packed, 0, (size_t)NB * HW * sizeof(unsigned long long), stream);

    compact_kernel<<<1, 256, 0, stream>>>(flag, q0, p1, cnt);
    pack_kernel<<<dim3(HW / 256, NC, NB), 256, 0, stream>>>(x, q0, p1, cnt, out);
    invc_kernel<<<dim3(HW / 256, NB), 256, 0, stream>>>(out, cnt, invc);
    argmax_kernel<<<dim3(NB * NT1 * NCH), 64, 0, stream>>>(out, invc, q0, p1, cnt, packed);
    shift_kernel<<<dim3(C2, NB), 256, 0, stream>>>(x, flag, packed, out);
}